// Round 3
// baseline (3151.813 us; speedup 1.0000x reference)
//
#include <hip/hip_runtime.h>
#include <math.h>

typedef __bf16 bf16;
typedef unsigned short u16;
typedef __bf16 bf16x8 __attribute__((ext_vector_type(8)));
typedef float f32x4 __attribute__((ext_vector_type(4)));

#define T_SEQ 2048
#define NB    2
#define CE    512
#define NH    8
#define HD    64
#define ROWS  4096
#define NBH   16
#define LDT   40   // GEMM LDS stride (32+8)
#define LDA   72   // attn LDS stride (64+8)

#define MFMA16(a,b,c) __builtin_amdgcn_mfma_f32_16x16x32_bf16((a),(b),(c),0,0,0)

// =====================================================================
// Sniffer: flags[0]=1 if float inputs are fp32 storage; flags[1]=1 if tokens int64
// =====================================================================
__global__ __launch_bounds__(256) void sniff(const u16* __restrict__ xs,
                                             const int* __restrict__ toks,
                                             int* __restrict__ flags)
{
  const int tid = threadIdx.x;
  int crazy = 0, ze = 0;
  for (int i = tid; i < 4096; i += 256) {
    int e = (xs[i] >> 7) & 0xFF;
    if (e >= 141) crazy++;
    if (((i & 1) == 0) && (xs[i] == 0)) ze++;
  }
  int zc = 0;
  for (int i = tid; i < 1024; i += 256)
    if (toks[2 * i + 1] == 0) zc++;
  __shared__ int r1[4], r2[4], r3[4];
#pragma unroll
  for (int o = 32; o; o >>= 1) {
    crazy += __shfl_down(crazy, o); ze += __shfl_down(ze, o); zc += __shfl_down(zc, o);
  }
  if ((tid & 63) == 0) { r1[tid >> 6] = crazy; r2[tid >> 6] = ze; r3[tid >> 6] = zc; }
  __syncthreads();
  if (tid == 0) {
    int c = r1[0] + r1[1] + r1[2] + r1[3];
    int z = r2[0] + r2[1] + r2[2] + r2[3];
    int t = r3[0] + r3[1] + r3[2] + r3[3];
    flags[0] = (z > 1500 || c > 64) ? 1 : 0;
    flags[1] = (t > 900) ? 1 : 0;
  }
}

static __device__ __forceinline__ float ldf(const void* src, size_t eoff, bool f32) {
  return f32 ? ((const float*)src)[eoff] : (float)((const bf16*)src)[eoff];
}

// =====================================================================
// Positional embedding
// =====================================================================
__global__ __launch_bounds__(256) void posembed(const void* __restrict__ xsrc,
                                                const int* __restrict__ toks,
                                                const int* __restrict__ flags,
                                                float* __restrict__ xf)
{
  const bool f32 = flags[0] != 0;
  const bool tok64 = flags[1] != 0;
  const int row = blockIdx.x;
  const int t = row >> 1, b = row & 1;
  const int tix = b * T_SEQ + t;
  const int tok = tok64 ? toks[2 * tix] : toks[tix];
  const int p = (tok != 0) ? (t + 1) : 0;
  const float kf = -0.0361193740f;
  for (int c = threadIdx.x; c < CE; c += 256) {
    float pe = 0.0f;
    if (p != 0) {
      int i = (c < 256) ? c : (c - 256);
      float freq = expf((float)i * kf);
      float ang = (float)p * freq;
      pe = (c < 256) ? sinf(ang) : cosf(ang);
    }
    xf[(size_t)row * CE + c] = ldf(xsrc, (size_t)row * CE + c, f32) + pe;
  }
}

// =====================================================================
// MFMA GEMM with split-K (blockIdx.z) and global->reg prefetch pipeline.
// C_z[M,N] = A[M,kb:ke]*W[N,kb:ke]^T (+bias if z==0) (+relu), fp32 out.
// Split-bf16 3-term numerics (proven rounds 1-2).
// =====================================================================
template<bool RELUF>
__global__ __launch_bounds__(256) void gemm_mfma(const void* __restrict__ A, int a_inp,
                                                 const void* __restrict__ Bw, size_t bwOff,
                                                 const void* __restrict__ bias, size_t biasOff,
                                                 const int* __restrict__ flags,
                                                 float* __restrict__ Cf,
                                                 int M, int N, int K, int kspan,
                                                 long long partStride)
{
  __shared__ __align__(16) bf16 Ah[128 * LDT];
  __shared__ __align__(16) bf16 Al[128 * LDT];
  __shared__ __align__(16) bf16 Bh[128 * LDT];
  __shared__ __align__(16) bf16 Bl[128 * LDT];
  const int fl = flags[0];
  const bool a_f32 = (a_inp == 0) ? true : (fl != 0);
  const bool b_f32 = (fl != 0);
  const int tid = threadIdx.x;
  const int m0 = blockIdx.y * 128, n0 = blockIdx.x * 128;
  const int srow = tid >> 1;
  const int skc  = (tid & 1) * 16;
  const int wid = tid >> 6, lane = tid & 63;
  const int wm = (wid >> 1) * 64, wn = (wid & 1) * 64;
  const int fr = lane & 15;
  const int fk = (lane >> 4) * 8;
  const int kb = blockIdx.z * kspan;
  const int ke = (kb + kspan < K) ? (kb + kspan) : K;
  float* Cp = Cf + (long long)blockIdx.z * partStride;
  f32x4 acc[4][4] = {};

  uint4 ra[4], rb[4];   // prefetch registers (16 f32 or 16 bf16 per matrix)
  auto loadA = [&](int k0) {
    size_t g = (size_t)(m0 + srow) * K + k0 + skc;
    if (a_f32) {
      const uint4* p = (const uint4*)((const float*)A + g);
      ra[0] = p[0]; ra[1] = p[1]; ra[2] = p[2]; ra[3] = p[3];
    } else {
      const uint4* p = (const uint4*)((const bf16*)A + g);
      ra[0] = p[0]; ra[1] = p[1];
    }
  };
  auto loadB = [&](int k0) {
    size_t g = bwOff + (size_t)(n0 + srow) * K + k0 + skc;
    if (b_f32) {
      const uint4* p = (const uint4*)((const float*)Bw + g);
      rb[0] = p[0]; rb[1] = p[1]; rb[2] = p[2]; rb[3] = p[3];
    } else {
      const uint4* p = (const uint4*)((const bf16*)Bw + g);
      rb[0] = p[0]; rb[1] = p[1];
    }
  };
  auto cvtStore = [&](const uint4* r, bool f32src, bool wantLo, bf16* Hs, bf16* Ls) {
    float v[16];
    if (f32src) {
      const float* f = (const float*)r;
#pragma unroll
      for (int q = 0; q < 16; q++) v[q] = f[q];
    } else {
      const bf16* c = (const bf16*)r;
#pragma unroll
      for (int q = 0; q < 16; q++) v[q] = (float)c[q];
    }
    bf16x8 h0, h1, l0, l1;
#pragma unroll
    for (int q = 0; q < 8; q++) {
      bf16 ha = (bf16)v[q], hb = (bf16)v[8 + q];
      h0[q] = ha; h1[q] = hb;
      l0[q] = (bf16)(v[q]     - (float)ha);
      l1[q] = (bf16)(v[8 + q] - (float)hb);
    }
    *(bf16x8*)&Hs[srow * LDT + skc]     = h0;
    *(bf16x8*)&Hs[srow * LDT + skc + 8] = h1;
    if (wantLo) {
      *(bf16x8*)&Ls[srow * LDT + skc]     = l0;
      *(bf16x8*)&Ls[srow * LDT + skc + 8] = l1;
    }
  };

  loadA(kb); loadB(kb);
  for (int k0 = kb; k0 < ke; k0 += 32) {
    __syncthreads();                 // previous compute done reading LDS
    cvtStore(ra, a_f32, a_f32, Ah, Al);
    cvtStore(rb, b_f32, b_f32, Bh, Bl);
    __syncthreads();
    if (k0 + 32 < ke) { loadA(k0 + 32); loadB(k0 + 32); }   // ride under MFMA
    bf16x8 ah[4], bh[4];
#pragma unroll
    for (int i = 0; i < 4; i++) ah[i] = *(const bf16x8*)&Ah[(wm + i*16 + fr) * LDT + fk];
#pragma unroll
    for (int j = 0; j < 4; j++) bh[j] = *(const bf16x8*)&Bh[(wn + j*16 + fr) * LDT + fk];
#pragma unroll
    for (int i = 0; i < 4; i++)
#pragma unroll
      for (int j = 0; j < 4; j++)
        acc[i][j] = MFMA16(ah[i], bh[j], acc[i][j]);
    if (a_f32) {
      bf16x8 al[4];
#pragma unroll
      for (int i = 0; i < 4; i++) al[i] = *(const bf16x8*)&Al[(wm + i*16 + fr) * LDT + fk];
#pragma unroll
      for (int i = 0; i < 4; i++)
#pragma unroll
        for (int j = 0; j < 4; j++)
          acc[i][j] = MFMA16(al[i], bh[j], acc[i][j]);
    }
    if (b_f32) {
      bf16x8 bl[4];
#pragma unroll
      for (int j = 0; j < 4; j++) bl[j] = *(const bf16x8*)&Bl[(wn + j*16 + fr) * LDT + fk];
#pragma unroll
      for (int i = 0; i < 4; i++)
#pragma unroll
        for (int j = 0; j < 4; j++)
          acc[i][j] = MFMA16(ah[i], bl[j], acc[i][j]);
    }
  }
  const int orow0 = m0 + wm + (lane >> 4) * 4;
  const int ocol0 = n0 + wn + (lane & 15);
  const bool addb = (blockIdx.z == 0);
#pragma unroll
  for (int j = 0; j < 4; j++) {
    int col = ocol0 + j * 16;
    float bv = addb ? ldf(bias, biasOff + col, b_f32) : 0.0f;
#pragma unroll
    for (int i = 0; i < 4; i++) {
#pragma unroll
      for (int r = 0; r < 4; r++) {
        float vv = acc[i][j][r] + bv;
        if (RELUF) vv = fmaxf(vv, 0.0f);
        Cp[(size_t)(orow0 + i * 16 + r) * N + col] = vv;
      }
    }
  }
}

// =====================================================================
// Prepass: split K (fp32, strided per-head rows) -> kh/kl bf16 [bh][s][64]
// =====================================================================
__global__ __launch_bounds__(256) void prep_split(const float* __restrict__ base, int ld, int ofs0,
                                                  bf16* __restrict__ oh, bf16* __restrict__ ol)
{
  const int bh = blockIdx.x, s0 = blockIdx.y * 64;
  const int b = bh >> 3, h = bh & 7, ofs = ofs0 + h * HD;
  const int tid = threadIdx.x;
#pragma unroll
  for (int it = 0; it < 16; ++it) {
    int idx = it * 256 + tid, r = idx >> 6, d = idx & 63;
    float v = base[(size_t)((s0 + r) * NB + b) * ld + ofs + d];
    bf16 hi = (bf16)v;
    size_t o = ((size_t)bh * T_SEQ + s0 + r) * 64 + d;
    oh[o] = hi; ol[o] = (bf16)(v - (float)hi);
  }
}

// =====================================================================
// Prepass: transpose+split V -> vth/vtl bf16 [bh][d][s]; per-64-chunk col sums
// =====================================================================
__global__ __launch_bounds__(256) void prep_vt(const float* __restrict__ base, int ld, int ofs0,
                                               bf16* __restrict__ vth, bf16* __restrict__ vtl,
                                               float* __restrict__ vcs)
{
  __shared__ float ts[128 * 65];
  const int bh = blockIdx.x, s0 = blockIdx.y * 128;
  const int b = bh >> 3, h = bh & 7, ofs = ofs0 + h * HD;
  const int tid = threadIdx.x;
#pragma unroll
  for (int it = 0; it < 32; ++it) {
    int idx = it * 256 + tid, r = idx >> 6, d = idx & 63;
    ts[r * 65 + d] = base[(size_t)((s0 + r) * NB + b) * ld + ofs + d];
  }
  __syncthreads();
  const int d = tid >> 2, sseg = (tid & 3) * 32;
#pragma unroll
  for (int g = 0; g < 4; ++g) {
    bf16x8 hv, lv;
#pragma unroll
    for (int q = 0; q < 8; ++q) {
      float v = ts[(sseg + g * 8 + q) * 65 + d];
      bf16 hi = (bf16)v; hv[q] = hi; lv[q] = (bf16)(v - (float)hi);
    }
    size_t o = ((size_t)bh * 64 + d) * T_SEQ + s0 + sseg + g * 8;
    *(bf16x8*)&vth[o] = hv;
    *(bf16x8*)&vtl[o] = lv;
  }
  if (tid < 128) {
    int c = tid >> 6, dd = tid & 63;
    float s = 0.0f;
    for (int j = 0; j < 64; ++j) s += ts[(c * 64 + j) * 65 + dd];
    vcs[((size_t)bh * 32 + blockIdx.y * 2 + c) * 64 + dd] = s;
  }
}

// pair heavy/light causal blocks on the same CU
__device__ __forceinline__ int remap_ty(int ty) { return (ty < 16) ? ty : 47 - ty; }

// =====================================================================
// Pass 1: min/max of masked raw scores via MFMA (3-term split-bf16).
// =====================================================================
template<bool MASK>
__global__ __launch_bounds__(256) void mm_mfma(const float* __restrict__ qbase, int qld, int qofs0,
                                               const bf16* __restrict__ kh, const bf16* __restrict__ kl,
                                               float* __restrict__ partial)
{
  __shared__ __align__(16) bf16 Qh[64 * LDA], Ql[64 * LDA], Kh[64 * LDA], Kl[64 * LDA];
  __shared__ float rn[4], rx[4];
  const int bh = blockIdx.x, tyr = remap_ty(blockIdx.y);
  const int t0 = tyr * 64;
  const int b = bh >> 3, h = bh & 7;
  const int qofs = qofs0 + h * HD;
  const int tid = threadIdx.x;
#pragma unroll
  for (int it = 0; it < 16; ++it) {
    int idx = it * 256 + tid, r = idx >> 6, d = idx & 63;
    float v = qbase[(size_t)((t0 + r) * NB + b) * qld + qofs + d] * 0.125f;
    bf16 hi = (bf16)v;
    Qh[r * LDA + d] = hi; Ql[r * LDA + d] = (bf16)(v - (float)hi);
  }
  const int wid = tid >> 6, lane = tid & 63;
  const int wm_ = (wid >> 1) * 32, wn_ = (wid & 1) * 32;
  const int fr = lane & 15, fko = (lane >> 4) * 8;
  const int crr = (lane >> 4) * 4, crc = lane & 15;
  const int cr = tid >> 2, cseg = (tid & 3) * 16;
  float mn = 1e30f, mx = -1e30f;
  const int nch = MASK ? (tyr + 1) : 32;
  for (int sc = 0; sc < nch; ++sc) {
    const int s0 = sc * 64;
    __syncthreads();
    {
      size_t go = ((size_t)bh * T_SEQ + s0 + cr) * 64 + cseg;
      *(bf16x8*)&Kh[cr * LDA + cseg]     = *(const bf16x8*)&kh[go];
      *(bf16x8*)&Kh[cr * LDA + cseg + 8] = *(const bf16x8*)&kh[go + 8];
      *(bf16x8*)&Kl[cr * LDA + cseg]     = *(const bf16x8*)&kl[go];
      *(bf16x8*)&Kl[cr * LDA + cseg + 8] = *(const bf16x8*)&kl[go + 8];
    }
    __syncthreads();
    f32x4 a4[2][2] = {};
#pragma unroll
    for (int ks = 0; ks < 2; ++ks) {
      bf16x8 aH[2], aL[2], bH[2], bL[2];
#pragma unroll
      for (int i = 0; i < 2; ++i) {
        aH[i] = *(const bf16x8*)&Qh[(wm_ + i*16 + fr) * LDA + ks*32 + fko];
        aL[i] = *(const bf16x8*)&Ql[(wm_ + i*16 + fr) * LDA + ks*32 + fko];
        bH[i] = *(const bf16x8*)&Kh[(wn_ + i*16 + fr) * LDA + ks*32 + fko];
        bL[i] = *(const bf16x8*)&Kl[(wn_ + i*16 + fr) * LDA + ks*32 + fko];
      }
#pragma unroll
      for (int i = 0; i < 2; ++i)
#pragma unroll
        for (int j = 0; j < 2; ++j) {
          a4[i][j] = MFMA16(aH[i], bH[j], a4[i][j]);
          a4[i][j] = MFMA16(aL[i], bH[j], a4[i][j]);
          a4[i][j] = MFMA16(aH[i], bL[j], a4[i][j]);
        }
    }
#pragma unroll
    for (int i = 0; i < 2; ++i)
#pragma unroll
      for (int j = 0; j < 2; ++j)
#pragma unroll
        for (int r = 0; r < 4; ++r) {
          float w = a4[i][j][r];
          if (MASK) {
            int tg = t0 + wm_ + i*16 + crr + r;
            int sg = s0 + wn_ + j*16 + crc;
            if (sg > tg) w = 0.0f;
          }
          mn = fminf(mn, w); mx = fmaxf(mx, w);
        }
  }
#pragma unroll
  for (int o = 32; o; o >>= 1) { mn = fminf(mn, __shfl_down(mn, o)); mx = fmaxf(mx, __shfl_down(mx, o)); }
  if (lane == 0) { rn[wid] = mn; rx[wid] = mx; }
  __syncthreads();
  if (tid == 0) {
    int bidx = blockIdx.y * NBH + blockIdx.x;
    partial[2 * bidx]     = fminf(fminf(rn[0], rn[1]), fminf(rn[2], rn[3]));
    partial[2 * bidx + 1] = fmaxf(fmaxf(rx[0], rx[1]), fmaxf(rx[2], rx[3]));
  }
}

// reduce 512 partial pairs -> mmf
__global__ __launch_bounds__(512) void reduce_mm(const float* __restrict__ partial,
                                                 float* __restrict__ mmf)
{
  const int tid = threadIdx.x, w = tid >> 6, l = tid & 63;
  __shared__ float rn[8], rx[8];
  float mn = partial[2 * tid], mx = partial[2 * tid + 1];
#pragma unroll
  for (int o = 32; o; o >>= 1) { mn = fminf(mn, __shfl_down(mn, o)); mx = fmaxf(mx, __shfl_down(mx, o)); }
  if (l == 0) { rn[w] = mn; rx[w] = mx; }
  __syncthreads();
  if (tid == 0) {
    float a = 1e30f, c = -1e30f;
#pragma unroll
    for (int i = 0; i < 8; i++) { a = fminf(a, rn[i]); c = fmaxf(c, rx[i]); }
    mmf[0] = a; mmf[1] = c;
  }
}

// =====================================================================
// Pass 2: out = sum_s ((w_m - mn)*inv) * v[s] via MFMA (3-term PV).
// =====================================================================
template<bool MASK>
__global__ __launch_bounds__(256) void attn_mfma(const float* __restrict__ qbase, int qld, int qofs0,
                                                 const bf16* __restrict__ kh, const bf16* __restrict__ kl,
                                                 const bf16* __restrict__ vth, const bf16* __restrict__ vtl,
                                                 const float* __restrict__ vcs,
                                                 const float* __restrict__ mmf,
                                                 float* __restrict__ aout)
{
  __shared__ __align__(16) bf16 Qh[64 * LDA], Ql[64 * LDA];
  __shared__ __align__(16) bf16 Kh[64 * LDA], Kl[64 * LDA];
  __shared__ __align__(16) bf16 Vh[64 * LDA], Vl[64 * LDA];
  __shared__ __align__(16) bf16 Ph[64 * LDA], Pl[64 * LDA];
  const int bh = blockIdx.x, tyr = remap_ty(blockIdx.y);
  const int t0 = tyr * 64;
  const int b = bh >> 3, h = bh & 7;
  const int qofs = qofs0 + h * HD;
  const int tid = threadIdx.x;
  const float mn = mmf[0];
  const float inv = 1.0f / (mmf[1] - mmf[0]);
#pragma unroll
  for (int it = 0; it < 16; ++it) {
    int idx = it * 256 + tid, r = idx >> 6, d = idx & 63;
    float v = qbase[(size_t)((t0 + r) * NB + b) * qld + qofs + d] * 0.125f;
    bf16 hi = (bf16)v;
    Qh[r * LDA + d] = hi; Ql[r * LDA + d] = (bf16)(v - (float)hi);
  }
  const int wid = tid >> 6, lane = tid & 63;
  const int wm_ = (wid >> 1) * 32, wn_ = (wid & 1) * 32;
  const int fr = lane & 15, fko = (lane >> 4) * 8;
  const int crr = (lane >> 4) * 4, crc = lane & 15;
  const int cr = tid >> 2, cseg = (tid & 3) * 16;
  f32x4 o4[2][2] = {};
  const int nch = MASK ? (tyr + 1) : 32;
  for (int sc = 0; sc < nch; ++sc) {
    const int s0 = sc * 64;
    __syncthreads();
    {
      size_t go = ((size_t)bh * T_SEQ + s0 + cr) * 64 + cseg;
      *(bf16x8*)&Kh[cr * LDA + cseg]     = *(const bf16x8*)&kh[go];
      *(bf16x8*)&Kh[cr * LDA + cseg + 8] = *(const bf16x8*)&kh[go + 8];
      *(bf16x8*)&Kl[cr * LDA + cseg]     = *(const bf16x8*)&kl[go];
      *(bf16x8*)&Kl[cr * LDA + cseg + 8] = *(const bf16x8*)&kl[go + 8];
      size_t gv = ((size_t)bh * 64 + cr) * T_SEQ + s0 + cseg;
      *(bf16x8*)&Vh[cr * LDA + cseg]     = *(const bf16x8*)&vth[gv];
      *(bf16x8*)&Vh[cr * LDA + cseg + 8] = *(const bf16x8*)&vth[gv + 8];
      *(bf16x8*)&Vl[cr * LDA + cseg]     = *(const bf16x8*)&vtl[gv];
      *(bf16x8*)&Vl[cr * LDA + cseg + 8] = *(const bf16x8*)&vtl[gv + 8];
    }
    __syncthreads();
    f32x4 a4[2][2] = {};
#pragma unroll
    for (int ks = 0; ks < 2; ++ks) {
      bf16x8 aH[2], aL[2], bH[2], bL[2];
#pragma unroll
      for (int i = 0; i < 2; ++i) {
        aH[i] = *(const bf16x8*)&Qh[(wm_ + i*16 + fr) * LDA + ks*32 + fko];
        aL[i] = *(const bf16x8*)&Ql[(wm_ + i*16 + fr) * LDA + ks*32 + fko];
        bH[i] = *(const bf16x8*)&Kh[(wn_ + i*16 + fr) * LDA + ks*32 + fko];
        bL[i] = *(const bf16x8*)&Kl[(wn_ + i*16 + fr) * LDA + ks*32 + fko];
      }
#pragma unroll
      for (int i = 0; i < 2; ++i)
#pragma unroll
        for (int j = 0; j < 2; ++j) {
          a4[i][j] = MFMA16(aH[i], bH[j], a4[i][j]);
          a4[i][j] = MFMA16(aL[i], bH[j], a4[i][j]);
          a4[i][j] = MFMA16(aH[i], bL[j], a4[i][j]);
        }
    }
#pragma unroll
    for (int i = 0; i < 2; ++i)
#pragma unroll
      for (int j = 0; j < 2; ++j)
#pragma unroll
        for (int r = 0; r < 4; ++r) {
          int tl = wm_ + i*16 + crr + r;
          int sl = wn_ + j*16 + crc;
          float w = a4[i][j][r];
          if (MASK && (s0 + sl) > (t0 + tl)) w = 0.0f;
          float p = (w - mn) * inv;
          bf16 ph = (bf16)p;
          Ph[tl * LDA + sl] = ph;
          Pl[tl * LDA + sl] = (bf16)(p - (float)ph);
        }
    __syncthreads();
#pragma unroll
    for (int ks = 0; ks < 2; ++ks) {
      bf16x8 pH[2], pL[2], vH[2], vL[2];
#pragma unroll
      for (int i = 0; i < 2; ++i) {
        pH[i] = *(const bf16x8*)&Ph[(wm_ + i*16 + fr) * LDA + ks*32 + fko];
        pL[i] = *(const bf16x8*)&Pl[(wm_ + i*16 + fr) * LDA + ks*32 + fko];
        vH[i] = *(const bf16x8*)&Vh[(wn_ + i*16 + fr) * LDA + ks*32 + fko];
        vL[i] = *(const bf16x8*)&Vl[(wn_ + i*16 + fr) * LDA + ks*32 + fko];
      }
#pragma unroll
      for (int i = 0; i < 2; ++i)
#pragma unroll
        for (int j = 0; j < 2; ++j) {
          o4[i][j] = MFMA16(pH[i], vH[j], o4[i][j]);
          o4[i][j] = MFMA16(pL[i], vH[j], o4[i][j]);
          o4[i][j] = MFMA16(pH[i], vL[j], o4[i][j]);
        }
    }
  }
  if (MASK && nch < 32) {
    const float c = (0.0f - mn) * inv;
#pragma unroll
    for (int j = 0; j < 2; ++j) {
      float s = 0.0f;
      for (int ch = nch; ch < 32; ++ch)
        s += vcs[((size_t)bh * 32 + ch) * 64 + wn_ + j*16 + crc];
      float add = c * s;
#pragma unroll
      for (int i = 0; i < 2; ++i)
#pragma unroll
        for (int r = 0; r < 4; ++r) o4[i][j][r] += add;
    }
  }
#pragma unroll
  for (int i = 0; i < 2; ++i)
#pragma unroll
    for (int j = 0; j < 2; ++j)
#pragma unroll
      for (int r = 0; r < 4; ++r) {
        int tl = wm_ + i*16 + crr + r;
        int dl = wn_ + j*16 + crc;
        aout[(size_t)((t0 + tl) * NB + b) * CE + h * HD + dl] = o4[i][j][r];
      }
}

// =====================================================================
// LayerNorm(res + sum of NP partial buffers)
// =====================================================================
template<int NP>
__global__ __launch_bounds__(256) void ln_sum(const float* __restrict__ res,
                                              const float* __restrict__ p, long long pstride,
                                              const void* __restrict__ g, const void* __restrict__ be,
                                              size_t goff, const int* __restrict__ flags,
                                              float* __restrict__ xfo)
{
  __shared__ float red[4];
  const bool fl = flags[0] != 0;
  const int tid = threadIdx.x;
  const size_t base = (size_t)blockIdx.x * CE;
  float a  = res[base + tid];
  float b2 = res[base + tid + 256];
#pragma unroll
  for (int k = 0; k < NP; k++) {
    a  += p[(long long)k * pstride + base + tid];
    b2 += p[(long long)k * pstride + base + tid + 256];
  }
  float s = a + b2;
#pragma unroll
  for (int o = 32; o; o >>= 1) s += __shfl_down(s, o);
  if ((tid & 63) == 0) red[tid >> 6] = s;
  __syncthreads();
  float mu = (red[0] + red[1] + red[2] + red[3]) * (1.0f / 512.0f);
  __syncthreads();
  float da = a - mu, db = b2 - mu;
  float q = da * da + db * db;
#pragma unroll
  for (int o = 32; o; o >>= 1) q += __shfl_down(q, o);
  if ((tid & 63) == 0) red[tid >> 6] = q;
  __syncthreads();
  float var = (red[0] + red[1] + red[2] + red[3]) * (1.0f / 512.0f);
  float rs = rsqrtf(var + 1e-20f);
  xfo[base + tid]       = da * rs * ldf(g, goff + tid, fl)       + ldf(be, goff + tid, fl);
  xfo[base + tid + 256] = db * rs * ldf(g, goff + tid + 256, fl) + ldf(be, goff + tid + 256, fl);
}

// =====================================================================
extern "C" void kernel_launch(void* const* d_in, const int* in_sizes, int n_in,
                              void* d_out, int out_size, void* d_ws, size_t ws_size,
                              hipStream_t stream)
{
  (void)in_sizes; (void)n_in; (void)out_size; (void)ws_size;
  const void* x_in   = d_in[0];
  const void* enc_in = d_in[1];
  const int*  tokens = (const int*)d_in[2];
  const void* sWqkv = d_in[3];
  const void* sbqkv = d_in[4];
  const void* sWo   = d_in[5];
  const void* sbo   = d_in[6];
  const void* cWqkv = d_in[7];
  const void* cbqkv = d_in[8];
  const void* cWo   = d_in[9];
  const void* cbo   = d_in[10];
  const void* fc1w  = d_in[11];
  const void* fc1b  = d_in[12];
  const void* fc2w  = d_in[13];
  const void* fc2b  = d_in[14];
  const void* ln1g  = d_in[15];
  const void* ln1b  = d_in[16];
  const void* ln2g  = d_in[17];
  const void* ln2b  = d_in[18];
  const void* ln3g  = d_in[19];
  const void* ln3b  = d_in[20];

  char* ws = (char*)d_ws;
  size_t off = 0;
  auto alloc = [&](size_t bytes) -> char* {
    char* p = ws + off;
    off += (bytes + 255) & ~(size_t)255;
    return p;
  };
  // ~72.6 MiB total
  int*   flags   = (int*)  alloc(256);
  float* mmf     = (float*)alloc(256);
  float* partial = (float*)alloc(4096);
  float* xf      = (float*)alloc((size_t)ROWS * CE * 4);       //  8 MiB
  float* y       = (float*)alloc((size_t)ROWS * CE * 4);       //  8 MiB
  float* qkv     = (float*)alloc((size_t)ROWS * 1536 * 4);     // 24 MiB
  float* pblk    = (float*)alloc((size_t)ROWS * CE * 4 * 2);   // 16 MiB split-K partials
  bf16*  khb     = (bf16*) alloc((size_t)16 * T_SEQ * 64 * 2); // 4 MiB
  bf16*  klb     = (bf16*) alloc((size_t)16 * T_SEQ * 64 * 2); // 4 MiB
  bf16*  vth     = (bf16*) alloc((size_t)16 * 64 * T_SEQ * 2); // 4 MiB
  bf16*  vtl     = (bf16*) alloc((size_t)16 * 64 * T_SEQ * 2); // 4 MiB
  float* vcs     = (float*)alloc((size_t)16 * 32 * 64 * 4);    // 128 KiB
  float* kvb = qkv + (size_t)ROWS * 512;
  const long long PS_FULL = (long long)ROWS * CE;      // 4096*512 partial stride
  const long long PS_HALF = (long long)2048 * CE;      // 2048*512 partial stride

  sniff<<<1, 256, 0, stream>>>((const u16*)x_in, tokens, flags);
  posembed<<<ROWS, 256, 0, stream>>>(x_in, tokens, flags, xf);

  for (int l = 0; l < 4; l++) {
    // ---------------- self-attention ----------------
    gemm_mfma<false><<<dim3(12, 32, 1), 256, 0, stream>>>(
        xf, 0, sWqkv, (size_t)l * 1536 * 512, sbqkv, (size_t)l * 1536, flags, qkv,
        ROWS, 1536, 512, 512, 0);
    prep_split<<<dim3(16, 32), 256, 0, stream>>>(qkv, 1536, 512, khb, klb);
    prep_vt<<<dim3(16, 16), 256, 0, stream>>>(qkv, 1536, 1024, vth, vtl, vcs);
    mm_mfma<true><<<dim3(NBH, 32), 256, 0, stream>>>(qkv, 1536, 0, khb, klb, partial);
    reduce_mm<<<1, 512, 0, stream>>>(partial, mmf);
    attn_mfma<true><<<dim3(NBH, 32), 256, 0, stream>>>(qkv, 1536, 0, khb, klb, vth, vtl, vcs, mmf, y);
    gemm_mfma<false><<<dim3(4, 32, 2), 256, 0, stream>>>(   // split-K2 -> 256 blocks
        y, 0, sWo, (size_t)l * 512 * 512, sbo, (size_t)l * 512, flags, pblk,
        ROWS, 512, 512, 256, PS_FULL);
    ln_sum<2><<<ROWS, 256, 0, stream>>>(xf, pblk, PS_FULL, ln1g, ln1b, (size_t)l * 512, flags, xf);

    // ---------------- cross-attention ----------------
    gemm_mfma<false><<<dim3(4, 32, 1), 256, 0, stream>>>(
        xf, 0, cWqkv, (size_t)l * 1536 * 512, cbqkv, (size_t)l * 1536, flags, qkv,
        ROWS, 512, 512, 512, 0);
    gemm_mfma<false><<<dim3(8, 32, 1), 256, 0, stream>>>(
        enc_in, 1, cWqkv, (size_t)l * 1536 * 512 + (size_t)512 * 512, cbqkv, (size_t)l * 1536 + 512,
        flags, kvb, ROWS, 1024, 512, 512, 0);
    prep_split<<<dim3(16, 32), 256, 0, stream>>>(kvb, 1024, 0, khb, klb);
    prep_vt<<<dim3(16, 16), 256, 0, stream>>>(kvb, 1024, 512, vth, vtl, vcs);
    mm_mfma<false><<<dim3(NBH, 32), 256, 0, stream>>>(qkv, 512, 0, khb, klb, partial);
    reduce_mm<<<1, 512, 0, stream>>>(partial, mmf);
    attn_mfma<false><<<dim3(NBH, 32), 256, 0, stream>>>(qkv, 512, 0, khb, klb, vth, vtl, vcs, mmf, y);
    gemm_mfma<false><<<dim3(4, 32, 2), 256, 0, stream>>>(   // split-K2
        y, 0, cWo, (size_t)l * 512 * 512, cbo, (size_t)l * 512, flags, pblk,
        ROWS, 512, 512, 256, PS_FULL);
    ln_sum<2><<<ROWS, 256, 0, stream>>>(xf, pblk, PS_FULL, ln2g, ln2b, (size_t)l * 512, flags, xf);

    // ---------------- FFN (two row-halves; h in qkv[0:16MiB]) ----------------
    for (int half = 0; half < 2; half++) {
      const float* Ain = xf + (size_t)half * 2048 * 512;
      gemm_mfma<true><<<dim3(16, 16, 1), 256, 0, stream>>>(
          Ain, 0, fc1w, (size_t)l * 2048 * 512, fc1b, (size_t)l * 2048, flags, qkv,
          2048, 2048, 512, 512, 0);
      gemm_mfma<false><<<dim3(4, 16, 4), 256, 0, stream>>>(  // split-K4 -> 256 blocks
          qkv, 0, fc2w, (size_t)l * 512 * 2048, fc2b, (size_t)l * 512, flags, pblk,
          2048, 512, 2048, 512, PS_HALF);
      float* lnout = ((l == 3) ? (float*)d_out : xf) + (size_t)half * 2048 * 512;
      ln_sum<4><<<2048, 256, 0, stream>>>(Ain, pblk, PS_HALF, ln3g, ln3b, (size_t)l * 512, flags, lnout);
    }
  }
}

// Round 4
// 2776.717 us; speedup vs baseline: 1.1351x; 1.1351x over previous
//
#include <hip/hip_runtime.h>
#include <math.h>

typedef __bf16 bf16;
typedef unsigned short u16;
typedef __bf16 bf16x8 __attribute__((ext_vector_type(8)));
typedef float f32x4 __attribute__((ext_vector_type(4)));

#define T_SEQ 2048
#define NB    2
#define CE    512
#define NH    8
#define HD    64
#define ROWS  4096
#define NBH   16
#define LDT   40   // GEMM LDS stride (32+8)
#define LDA   72   // attn LDS stride (64+8)

#define MFMA16(a,b,c) __builtin_amdgcn_mfma_f32_16x16x32_bf16((a),(b),(c),0,0,0)

// =====================================================================
// Sniffer: flags[0]=1 if float inputs are fp32 storage; flags[1]=1 if tokens int64
// =====================================================================
__global__ __launch_bounds__(256) void sniff(const u16* __restrict__ xs,
                                             const int* __restrict__ toks,
                                             int* __restrict__ flags)
{
  const int tid = threadIdx.x;
  int crazy = 0, ze = 0;
  for (int i = tid; i < 4096; i += 256) {
    int e = (xs[i] >> 7) & 0xFF;
    if (e >= 141) crazy++;
    if (((i & 1) == 0) && (xs[i] == 0)) ze++;
  }
  int zc = 0;
  for (int i = tid; i < 1024; i += 256)
    if (toks[2 * i + 1] == 0) zc++;
  __shared__ int r1[4], r2[4], r3[4];
#pragma unroll
  for (int o = 32; o; o >>= 1) {
    crazy += __shfl_down(crazy, o); ze += __shfl_down(ze, o); zc += __shfl_down(zc, o);
  }
  if ((tid & 63) == 0) { r1[tid >> 6] = crazy; r2[tid >> 6] = ze; r3[tid >> 6] = zc; }
  __syncthreads();
  if (tid == 0) {
    int c = r1[0] + r1[1] + r1[2] + r1[3];
    int z = r2[0] + r2[1] + r2[2] + r2[3];
    int t = r3[0] + r3[1] + r3[2] + r3[3];
    flags[0] = (z > 1500 || c > 64) ? 1 : 0;
    flags[1] = (t > 900) ? 1 : 0;
  }
}

static __device__ __forceinline__ float ldf(const void* src, size_t eoff, bool f32) {
  return f32 ? ((const float*)src)[eoff] : (float)((const bf16*)src)[eoff];
}

// =====================================================================
// Positional embedding
// =====================================================================
__global__ __launch_bounds__(256) void posembed(const void* __restrict__ xsrc,
                                                const int* __restrict__ toks,
                                                const int* __restrict__ flags,
                                                float* __restrict__ xf)
{
  const bool f32 = flags[0] != 0;
  const bool tok64 = flags[1] != 0;
  const int row = blockIdx.x;
  const int t = row >> 1, b = row & 1;
  const int tix = b * T_SEQ + t;
  const int tok = tok64 ? toks[2 * tix] : toks[tix];
  const int p = (tok != 0) ? (t + 1) : 0;
  const float kf = -0.0361193740f;
  for (int c = threadIdx.x; c < CE; c += 256) {
    float pe = 0.0f;
    if (p != 0) {
      int i = (c < 256) ? c : (c - 256);
      float freq = expf((float)i * kf);
      float ang = (float)p * freq;
      pe = (c < 256) ? sinf(ang) : cosf(ang);
    }
    xf[(size_t)row * CE + c] = ldf(xsrc, (size_t)row * CE + c, f32) + pe;
  }
}

// =====================================================================
// MFMA GEMM, split-K (blockIdx.z), global->reg prefetch pipeline.
// C_z[M,N] = A[M,kb:ke]*W[N,kb:ke]^T (+bias if z==0) (+relu), fp32 out.
// AFFINE: A element a' = inv*a - cmn*vsum[rowpar][col]  (attention affine fixup
// fused into the Wo projection's A-staging; vsum = total V colsum per (b,col)).
// Split-bf16 3-term numerics throughout (proven rounds 1-3).
// =====================================================================
template<bool RELUF, bool AFFINE>
__global__ __launch_bounds__(256) void gemm_mfma(const void* __restrict__ A, int a_inp,
                                                 const void* __restrict__ Bw, size_t bwOff,
                                                 const void* __restrict__ bias, size_t biasOff,
                                                 const int* __restrict__ flags,
                                                 float* __restrict__ Cf,
                                                 int M, int N, int K, int kspan,
                                                 long long partStride,
                                                 const float* __restrict__ mmf,
                                                 const float* __restrict__ vsum)
{
  __shared__ __align__(16) bf16 Ah[128 * LDT];
  __shared__ __align__(16) bf16 Al[128 * LDT];
  __shared__ __align__(16) bf16 Bh[128 * LDT];
  __shared__ __align__(16) bf16 Bl[128 * LDT];
  const int fl = flags[0];
  const bool a_f32 = (a_inp == 0) ? true : (fl != 0);
  const bool b_f32 = (fl != 0);
  const int tid = threadIdx.x;
  const int m0 = blockIdx.y * 128, n0 = blockIdx.x * 128;
  const int srow = tid >> 1;
  const int skc  = (tid & 1) * 16;
  const int wid = tid >> 6, lane = tid & 63;
  const int wm = (wid >> 1) * 64, wn = (wid & 1) * 64;
  const int fr = lane & 15;
  const int fk = (lane >> 4) * 8;
  const int kb = blockIdx.z * kspan;
  const int ke = (kb + kspan < K) ? (kb + kspan) : K;
  float* Cp = Cf + (long long)blockIdx.z * partStride;
  const int arow1 = (m0 + srow) & 1;
  float inv_ = 0.0f, cmn_ = 0.0f;
  if (AFFINE) { inv_ = 1.0f / (mmf[1] - mmf[0]); cmn_ = mmf[0] * inv_; }
  f32x4 acc[4][4] = {};

  uint4 ra[4], rb[4];
  auto loadA = [&](int k0) {
    size_t g = (size_t)(m0 + srow) * K + k0 + skc;
    if (a_f32) {
      const uint4* p = (const uint4*)((const float*)A + g);
      ra[0] = p[0]; ra[1] = p[1]; ra[2] = p[2]; ra[3] = p[3];
    } else {
      const uint4* p = (const uint4*)((const bf16*)A + g);
      ra[0] = p[0]; ra[1] = p[1];
    }
  };
  auto loadB = [&](int k0) {
    size_t g = bwOff + (size_t)(n0 + srow) * K + k0 + skc;
    if (b_f32) {
      const uint4* p = (const uint4*)((const float*)Bw + g);
      rb[0] = p[0]; rb[1] = p[1]; rb[2] = p[2]; rb[3] = p[3];
    } else {
      const uint4* p = (const uint4*)((const bf16*)Bw + g);
      rb[0] = p[0]; rb[1] = p[1];
    }
  };
  auto cvtStore = [&](const uint4* r, bool f32src, bool wantLo, bf16* Hs, bf16* Ls) {
    float v[16];
    if (f32src) {
      const float* f = (const float*)r;
#pragma unroll
      for (int q = 0; q < 16; q++) v[q] = f[q];
    } else {
      const bf16* c = (const bf16*)r;
#pragma unroll
      for (int q = 0; q < 16; q++) v[q] = (float)c[q];
    }
    bf16x8 h0, h1, l0, l1;
#pragma unroll
    for (int q = 0; q < 8; q++) {
      bf16 ha = (bf16)v[q], hb = (bf16)v[8 + q];
      h0[q] = ha; h1[q] = hb;
      l0[q] = (bf16)(v[q]     - (float)ha);
      l1[q] = (bf16)(v[8 + q] - (float)hb);
    }
    *(bf16x8*)&Hs[srow * LDT + skc]     = h0;
    *(bf16x8*)&Hs[srow * LDT + skc + 8] = h1;
    if (wantLo) {
      *(bf16x8*)&Ls[srow * LDT + skc]     = l0;
      *(bf16x8*)&Ls[srow * LDT + skc + 8] = l1;
    }
  };

  loadA(kb); loadB(kb);
  for (int k0 = kb; k0 < ke; k0 += 32) {
    __syncthreads();
    if (AFFINE) {      // apply affine fixup to raw A regs before split
      float* f = (float*)ra;
      const float* vs = vsum + arow1 * 512 + k0 + skc;
#pragma unroll
      for (int q = 0; q < 16; q++) f[q] = inv_ * f[q] - cmn_ * vs[q];
    }
    cvtStore(ra, a_f32, a_f32, Ah, Al);
    cvtStore(rb, b_f32, b_f32, Bh, Bl);
    __syncthreads();
    if (k0 + 32 < ke) { loadA(k0 + 32); loadB(k0 + 32); }
    bf16x8 ah[4], bh[4];
#pragma unroll
    for (int i = 0; i < 4; i++) ah[i] = *(const bf16x8*)&Ah[(wm + i*16 + fr) * LDT + fk];
#pragma unroll
    for (int j = 0; j < 4; j++) bh[j] = *(const bf16x8*)&Bh[(wn + j*16 + fr) * LDT + fk];
#pragma unroll
    for (int i = 0; i < 4; i++)
#pragma unroll
      for (int j = 0; j < 4; j++)
        acc[i][j] = MFMA16(ah[i], bh[j], acc[i][j]);
    if (a_f32) {
      bf16x8 al[4];
#pragma unroll
      for (int i = 0; i < 4; i++) al[i] = *(const bf16x8*)&Al[(wm + i*16 + fr) * LDT + fk];
#pragma unroll
      for (int i = 0; i < 4; i++)
#pragma unroll
        for (int j = 0; j < 4; j++)
          acc[i][j] = MFMA16(al[i], bh[j], acc[i][j]);
    }
    if (b_f32) {
      bf16x8 bl[4];
#pragma unroll
      for (int j = 0; j < 4; j++) bl[j] = *(const bf16x8*)&Bl[(wn + j*16 + fr) * LDT + fk];
#pragma unroll
      for (int i = 0; i < 4; i++)
#pragma unroll
        for (int j = 0; j < 4; j++)
          acc[i][j] = MFMA16(ah[i], bl[j], acc[i][j]);
    }
  }
  const int orow0 = m0 + wm + (lane >> 4) * 4;
  const int ocol0 = n0 + wn + (lane & 15);
  const bool addb = (blockIdx.z == 0);
#pragma unroll
  for (int j = 0; j < 4; j++) {
    int col = ocol0 + j * 16;
    float bv = addb ? ldf(bias, biasOff + col, b_f32) : 0.0f;
#pragma unroll
    for (int i = 0; i < 4; i++) {
#pragma unroll
      for (int r = 0; r < 4; r++) {
        float vv = acc[i][j][r] + bv;
        if (RELUF) vv = fmaxf(vv, 0.0f);
        Cp[(size_t)(orow0 + i * 16 + r) * N + col] = vv;
      }
    }
  }
}

// =====================================================================
// Fused K/V prepass: K split -> kh/kl [bh][s][64]; V transpose+split ->
// vth/vtl [bh][d][s]; per-64-chunk V col sums -> vcs[bh][32][64].
// grid (16 bh, 32 s-blocks of 64)
// =====================================================================
__global__ __launch_bounds__(256) void prep_kv(const float* __restrict__ base, int ld,
                                               int kofs0, int vofs0,
                                               bf16* __restrict__ kh, bf16* __restrict__ kl,
                                               bf16* __restrict__ vth, bf16* __restrict__ vtl,
                                               float* __restrict__ vcs)
{
  __shared__ float ts[64 * 65];
  const int bh = blockIdx.x, s0 = blockIdx.y * 64;
  const int b = bh >> 3, h = bh & 7;
  const int kofs = kofs0 + h * HD, vofs = vofs0 + h * HD;
  const int tid = threadIdx.x;
#pragma unroll
  for (int it = 0; it < 16; ++it) {
    int idx = it * 256 + tid, r = idx >> 6, d = idx & 63;
    size_t rowb = (size_t)((s0 + r) * NB + b) * ld;
    float v = base[rowb + kofs + d];
    bf16 hi = (bf16)v;
    size_t o = ((size_t)bh * T_SEQ + s0 + r) * 64 + d;
    kh[o] = hi; kl[o] = (bf16)(v - (float)hi);
    ts[r * 65 + d] = base[rowb + vofs + d];
  }
  __syncthreads();
  const int d = tid >> 2, sseg = (tid & 3) * 16;
  bf16x8 hv0, lv0, hv1, lv1;
#pragma unroll
  for (int q = 0; q < 8; ++q) {
    float v0 = ts[(sseg + q) * 65 + d];
    float v1 = ts[(sseg + 8 + q) * 65 + d];
    bf16 h0 = (bf16)v0, h1 = (bf16)v1;
    hv0[q] = h0; lv0[q] = (bf16)(v0 - (float)h0);
    hv1[q] = h1; lv1[q] = (bf16)(v1 - (float)h1);
  }
  size_t o = ((size_t)bh * 64 + d) * T_SEQ + s0 + sseg;
  *(bf16x8*)&vth[o]     = hv0;
  *(bf16x8*)&vth[o + 8] = hv1;
  *(bf16x8*)&vtl[o]     = lv0;
  *(bf16x8*)&vtl[o + 8] = lv1;
  if (tid < 64) {
    float s = 0.0f;
    for (int j = 0; j < 64; ++j) s += ts[j * 65 + tid];
    vcs[((size_t)bh * 32 + blockIdx.y) * 64 + tid] = s;
  }
}

// pair heavy/light causal blocks on the same CU
__device__ __forceinline__ int remap_ty(int ty) { return (ty < 16) ? ty : 47 - ty; }

// =====================================================================
// Fused attention pass (affine trick): one sweep computes
//   raw masked scores w (masked -> exact 0), global min/max partials,
//   and raw PV:  pvout = sum_s w*v  (independent of mn/mx!).
// Final normalization out = inv*pvout - mn*inv*Vsum is applied in the
// following Wo GEMM (AFFINE path). grid (16 bh, 32 t-blocks of 64)
// =====================================================================
template<bool MASK>
__global__ __launch_bounds__(256) void fattn(const float* __restrict__ qbase, int qld, int qofs0,
                                             const bf16* __restrict__ kh, const bf16* __restrict__ kl,
                                             const bf16* __restrict__ vth, const bf16* __restrict__ vtl,
                                             float* __restrict__ partial,
                                             float* __restrict__ pvout)
{
  __shared__ __align__(16) bf16 Qh[64 * LDA], Ql[64 * LDA];
  __shared__ __align__(16) bf16 Kh[64 * LDA], Kl[64 * LDA];
  __shared__ __align__(16) bf16 Vh[64 * LDA], Vl[64 * LDA];
  __shared__ __align__(16) bf16 Ph[64 * LDA], Pl[64 * LDA];
  __shared__ float rn[4], rx[4];
  const int bh = blockIdx.x, tyr = remap_ty(blockIdx.y);
  const int t0 = tyr * 64;
  const int b = bh >> 3, h = bh & 7;
  const int qofs = qofs0 + h * HD;
  const int tid = threadIdx.x;
#pragma unroll
  for (int it = 0; it < 16; ++it) {
    int idx = it * 256 + tid, r = idx >> 6, d = idx & 63;
    float v = qbase[(size_t)((t0 + r) * NB + b) * qld + qofs + d] * 0.125f;
    bf16 hi = (bf16)v;
    Qh[r * LDA + d] = hi; Ql[r * LDA + d] = (bf16)(v - (float)hi);
  }
  const int wid = tid >> 6, lane = tid & 63;
  const int wm_ = (wid >> 1) * 32, wn_ = (wid & 1) * 32;
  const int fr = lane & 15, fko = (lane >> 4) * 8;
  const int crr = (lane >> 4) * 4, crc = lane & 15;
  const int cr = tid >> 2, cseg = (tid & 3) * 16;
  float mn = 1e30f, mx = -1e30f;
  f32x4 o4[2][2] = {};
  const int nch = MASK ? (tyr + 1) : 32;
  for (int sc = 0; sc < nch; ++sc) {
    const int s0 = sc * 64;
    __syncthreads();
    {
      size_t go = ((size_t)bh * T_SEQ + s0 + cr) * 64 + cseg;
      *(bf16x8*)&Kh[cr * LDA + cseg]     = *(const bf16x8*)&kh[go];
      *(bf16x8*)&Kh[cr * LDA + cseg + 8] = *(const bf16x8*)&kh[go + 8];
      *(bf16x8*)&Kl[cr * LDA + cseg]     = *(const bf16x8*)&kl[go];
      *(bf16x8*)&Kl[cr * LDA + cseg + 8] = *(const bf16x8*)&kl[go + 8];
      size_t gv = ((size_t)bh * 64 + cr) * T_SEQ + s0 + cseg;
      *(bf16x8*)&Vh[cr * LDA + cseg]     = *(const bf16x8*)&vth[gv];
      *(bf16x8*)&Vh[cr * LDA + cseg + 8] = *(const bf16x8*)&vth[gv + 8];
      *(bf16x8*)&Vl[cr * LDA + cseg]     = *(const bf16x8*)&vtl[gv];
      *(bf16x8*)&Vl[cr * LDA + cseg + 8] = *(const bf16x8*)&vtl[gv + 8];
    }
    __syncthreads();
    // ---- QK^T (3-term) ----
    f32x4 a4[2][2] = {};
#pragma unroll
    for (int ks = 0; ks < 2; ++ks) {
      bf16x8 aH[2], aL[2], bH[2], bL[2];
#pragma unroll
      for (int i = 0; i < 2; ++i) {
        aH[i] = *(const bf16x8*)&Qh[(wm_ + i*16 + fr) * LDA + ks*32 + fko];
        aL[i] = *(const bf16x8*)&Ql[(wm_ + i*16 + fr) * LDA + ks*32 + fko];
        bH[i] = *(const bf16x8*)&Kh[(wn_ + i*16 + fr) * LDA + ks*32 + fko];
        bL[i] = *(const bf16x8*)&Kl[(wn_ + i*16 + fr) * LDA + ks*32 + fko];
      }
#pragma unroll
      for (int i = 0; i < 2; ++i)
#pragma unroll
        for (int j = 0; j < 2; ++j) {
          a4[i][j] = MFMA16(aH[i], bH[j], a4[i][j]);
          a4[i][j] = MFMA16(aL[i], bH[j], a4[i][j]);
          a4[i][j] = MFMA16(aH[i], bL[j], a4[i][j]);
        }
    }
    // ---- mask, min/max, store raw w hi/lo ----
#pragma unroll
    for (int i = 0; i < 2; ++i)
#pragma unroll
      for (int j = 0; j < 2; ++j)
#pragma unroll
        for (int r = 0; r < 4; ++r) {
          int tl = wm_ + i*16 + crr + r;
          int sl = wn_ + j*16 + crc;
          float w = a4[i][j][r];
          if (MASK && (s0 + sl) > (t0 + tl)) w = 0.0f;   // w * tril: exact 0
          mn = fminf(mn, w); mx = fmaxf(mx, w);
          bf16 wh = (bf16)w;
          Ph[tl * LDA + sl] = wh;
          Pl[tl * LDA + sl] = (bf16)(w - (float)wh);
        }
    __syncthreads();
    // ---- raw PV (3-term): A = w [t][s], B = V^T [d][s] ----
#pragma unroll
    for (int ks = 0; ks < 2; ++ks) {
      bf16x8 pH[2], pL[2], vH[2], vL[2];
#pragma unroll
      for (int i = 0; i < 2; ++i) {
        pH[i] = *(const bf16x8*)&Ph[(wm_ + i*16 + fr) * LDA + ks*32 + fko];
        pL[i] = *(const bf16x8*)&Pl[(wm_ + i*16 + fr) * LDA + ks*32 + fko];
        vH[i] = *(const bf16x8*)&Vh[(wn_ + i*16 + fr) * LDA + ks*32 + fko];
        vL[i] = *(const bf16x8*)&Vl[(wn_ + i*16 + fr) * LDA + ks*32 + fko];
      }
#pragma unroll
      for (int i = 0; i < 2; ++i)
#pragma unroll
        for (int j = 0; j < 2; ++j) {
          o4[i][j] = MFMA16(pH[i], vH[j], o4[i][j]);
          o4[i][j] = MFMA16(pL[i], vH[j], o4[i][j]);
          o4[i][j] = MFMA16(pH[i], vL[j], o4[i][j]);
        }
    }
  }
  // raw PV out (normalization deferred to Wo GEMM's AFFINE path)
#pragma unroll
  for (int i = 0; i < 2; ++i)
#pragma unroll
    for (int j = 0; j < 2; ++j)
#pragma unroll
      for (int r = 0; r < 4; ++r) {
        int tl = wm_ + i*16 + crr + r;
        int dl = wn_ + j*16 + crc;
        pvout[(size_t)((t0 + tl) * NB + b) * CE + h * HD + dl] = o4[i][j][r];
      }
  // min/max partials
#pragma unroll
  for (int o = 32; o; o >>= 1) { mn = fminf(mn, __shfl_down(mn, o)); mx = fmaxf(mx, __shfl_down(mx, o)); }
  if (lane == 0) { rn[wid] = mn; rx[wid] = mx; }
  __syncthreads();
  if (tid == 0) {
    int bidx = blockIdx.y * NBH + blockIdx.x;
    partial[2 * bidx]     = fminf(fminf(rn[0], rn[1]), fminf(rn[2], rn[3]));
    partial[2 * bidx + 1] = fmaxf(fmaxf(rx[0], rx[1]), fmaxf(rx[2], rx[3]));
  }
}

// =====================================================================
// reduce 512 partial pairs -> mmf; also total V colsum vsum[2*512]
// (vsum[b*512 + h*64 + d] = sum over all s of V[bh][s][d])
// =====================================================================
__global__ __launch_bounds__(512) void reduce_mm(const float* __restrict__ partial,
                                                 const float* __restrict__ vcs,
                                                 float* __restrict__ mmf,
                                                 float* __restrict__ vsum)
{
  const int tid = threadIdx.x, w = tid >> 6, l = tid & 63;
  __shared__ float rn[8], rx[8];
  float mn = partial[2 * tid], mx = partial[2 * tid + 1];
#pragma unroll
  for (int o = 32; o; o >>= 1) { mn = fminf(mn, __shfl_down(mn, o)); mx = fmaxf(mx, __shfl_down(mx, o)); }
  if (l == 0) { rn[w] = mn; rx[w] = mx; }
  __syncthreads();
  if (tid == 0) {
    float a = 1e30f, c = -1e30f;
#pragma unroll
    for (int i = 0; i < 8; i++) { a = fminf(a, rn[i]); c = fmaxf(c, rx[i]); }
    mmf[0] = a; mmf[1] = c;
  }
  for (int e = tid; e < 1024; e += 512) {
    int bh = e >> 6, d = e & 63;
    float s = 0.0f;
#pragma unroll
    for (int ch = 0; ch < 32; ++ch) s += vcs[(size_t)bh * 2048 + ch * 64 + d];
    vsum[e] = s;   // e = bh*64+d = b*512 + (h*64+d)
  }
}

// =====================================================================
// LayerNorm(res + sum of NP partial buffers)
// =====================================================================
template<int NP>
__global__ __launch_bounds__(256) void ln_sum(const float* __restrict__ res,
                                              const float* __restrict__ p, long long pstride,
                                              const void* __restrict__ g, const void* __restrict__ be,
                                              size_t goff, const int* __restrict__ flags,
                                              float* __restrict__ xfo)
{
  __shared__ float red[4];
  const bool fl = flags[0] != 0;
  const int tid = threadIdx.x;
  const size_t base = (size_t)blockIdx.x * CE;
  float a  = res[base + tid];
  float b2 = res[base + tid + 256];
#pragma unroll
  for (int k = 0; k < NP; k++) {
    a  += p[(long long)k * pstride + base + tid];
    b2 += p[(long long)k * pstride + base + tid + 256];
  }
  float s = a + b2;
#pragma unroll
  for (int o = 32; o; o >>= 1) s += __shfl_down(s, o);
  if ((tid & 63) == 0) red[tid >> 6] = s;
  __syncthreads();
  float mu = (red[0] + red[1] + red[2] + red[3]) * (1.0f / 512.0f);
  __syncthreads();
  float da = a - mu, db = b2 - mu;
  float q = da * da + db * db;
#pragma unroll
  for (int o = 32; o; o >>= 1) q += __shfl_down(q, o);
  if ((tid & 63) == 0) red[tid >> 6] = q;
  __syncthreads();
  float var = (red[0] + red[1] + red[2] + red[3]) * (1.0f / 512.0f);
  float rs = rsqrtf(var + 1e-20f);
  xfo[base + tid]       = da * rs * ldf(g, goff + tid, fl)       + ldf(be, goff + tid, fl);
  xfo[base + tid + 256] = db * rs * ldf(g, goff + tid + 256, fl) + ldf(be, goff + tid + 256, fl);
}

// =====================================================================
extern "C" void kernel_launch(void* const* d_in, const int* in_sizes, int n_in,
                              void* d_out, int out_size, void* d_ws, size_t ws_size,
                              hipStream_t stream)
{
  (void)in_sizes; (void)n_in; (void)out_size; (void)ws_size;
  const void* x_in   = d_in[0];
  const void* enc_in = d_in[1];
  const int*  tokens = (const int*)d_in[2];
  const void* sWqkv = d_in[3];
  const void* sbqkv = d_in[4];
  const void* sWo   = d_in[5];
  const void* sbo   = d_in[6];
  const void* cWqkv = d_in[7];
  const void* cbqkv = d_in[8];
  const void* cWo   = d_in[9];
  const void* cbo   = d_in[10];
  const void* fc1w  = d_in[11];
  const void* fc1b  = d_in[12];
  const void* fc2w  = d_in[13];
  const void* fc2b  = d_in[14];
  const void* ln1g  = d_in[15];
  const void* ln1b  = d_in[16];
  const void* ln2g  = d_in[17];
  const void* ln2b  = d_in[18];
  const void* ln3g  = d_in[19];
  const void* ln3b  = d_in[20];

  char* ws = (char*)d_ws;
  size_t off = 0;
  auto alloc = [&](size_t bytes) -> char* {
    char* p = ws + off;
    off += (bytes + 255) & ~(size_t)255;
    return p;
  };
  // ~96.5 MiB total
  int*   flags   = (int*)  alloc(256);
  float* mmf     = (float*)alloc(256);
  float* vsum    = (float*)alloc(1024 * 4);
  float* partial = (float*)alloc(4096);
  float* xf      = (float*)alloc((size_t)ROWS * CE * 4);        //  8 MiB residual
  float* y       = (float*)alloc((size_t)ROWS * CE * 4);        //  8 MiB attn raw-PV
  float* qkv     = (float*)alloc((size_t)ROWS * 2048 * 4);      // 32 MiB proj / FFN h
  float* pblk    = (float*)alloc((size_t)ROWS * CE * 4 * 4);    // 32 MiB split-K partials
  bf16*  khb     = (bf16*) alloc((size_t)16 * T_SEQ * 64 * 2);  // 4 MiB
  bf16*  klb     = (bf16*) alloc((size_t)16 * T_SEQ * 64 * 2);  // 4 MiB
  bf16*  vth     = (bf16*) alloc((size_t)16 * 64 * T_SEQ * 2);  // 4 MiB
  bf16*  vtl     = (bf16*) alloc((size_t)16 * 64 * T_SEQ * 2);  // 4 MiB
  float* vcs     = (float*)alloc((size_t)16 * 32 * 64 * 4);     // 128 KiB
  float* kvb = qkv + (size_t)ROWS * 512;
  const long long PS_FULL = (long long)ROWS * CE;

  sniff<<<1, 256, 0, stream>>>((const u16*)x_in, tokens, flags);
  posembed<<<ROWS, 256, 0, stream>>>(x_in, tokens, flags, xf);

  for (int l = 0; l < 4; l++) {
    // ---------------- self-attention ----------------
    gemm_mfma<false, false><<<dim3(12, 32, 1), 256, 0, stream>>>(
        xf, 0, sWqkv, (size_t)l * 1536 * 512, sbqkv, (size_t)l * 1536, flags, qkv,
        ROWS, 1536, 512, 512, 0, nullptr, nullptr);
    prep_kv<<<dim3(16, 32), 256, 0, stream>>>(qkv, 1536, 512, 1024, khb, klb, vth, vtl, vcs);
    fattn<true><<<dim3(NBH, 32), 256, 0, stream>>>(qkv, 1536, 0, khb, klb, vth, vtl, partial, y);
    reduce_mm<<<1, 512, 0, stream>>>(partial, vcs, mmf, vsum);
    gemm_mfma<false, true><<<dim3(4, 32, 4), 256, 0, stream>>>(   // AFFINE Wo, split-K4
        y, 0, sWo, (size_t)l * 512 * 512, sbo, (size_t)l * 512, flags, pblk,
        ROWS, 512, 512, 128, PS_FULL, mmf, vsum);
    ln_sum<4><<<ROWS, 256, 0, stream>>>(xf, pblk, PS_FULL, ln1g, ln1b, (size_t)l * 512, flags, xf);

    // ---------------- cross-attention ----------------
    gemm_mfma<false, false><<<dim3(4, 32, 1), 256, 0, stream>>>(
        xf, 0, cWqkv, (size_t)l * 1536 * 512, cbqkv, (size_t)l * 1536, flags, qkv,
        ROWS, 512, 512, 512, 0, nullptr, nullptr);
    gemm_mfma<false, false><<<dim3(8, 32, 1), 256, 0, stream>>>(
        enc_in, 1, cWqkv, (size_t)l * 1536 * 512 + (size_t)512 * 512, cbqkv, (size_t)l * 1536 + 512,
        flags, kvb, ROWS, 1024, 512, 512, 0, nullptr, nullptr);
    prep_kv<<<dim3(16, 32), 256, 0, stream>>>(kvb, 1024, 0, 512, khb, klb, vth, vtl, vcs);
    fattn<false><<<dim3(NBH, 32), 256, 0, stream>>>(qkv, 512, 0, khb, klb, vth, vtl, partial, y);
    reduce_mm<<<1, 512, 0, stream>>>(partial, vcs, mmf, vsum);
    gemm_mfma<false, true><<<dim3(4, 32, 4), 256, 0, stream>>>(   // AFFINE cWo, split-K4
        y, 0, cWo, (size_t)l * 512 * 512, cbo, (size_t)l * 512, flags, pblk,
        ROWS, 512, 512, 128, PS_FULL, mmf, vsum);
    ln_sum<4><<<ROWS, 256, 0, stream>>>(xf, pblk, PS_FULL, ln2g, ln2b, (size_t)l * 512, flags, xf);

    // ---------------- FFN (batched M=4096) ----------------
    gemm_mfma<true, false><<<dim3(16, 32, 1), 256, 0, stream>>>(
        xf, 0, fc1w, (size_t)l * 2048 * 512, fc1b, (size_t)l * 2048, flags, qkv,
        ROWS, 2048, 512, 512, 0, nullptr, nullptr);
    gemm_mfma<false, false><<<dim3(4, 32, 4), 256, 0, stream>>>(  // split-K4
        qkv, 0, fc2w, (size_t)l * 512 * 2048, fc2b, (size_t)l * 512, flags, pblk,
        ROWS, 512, 2048, 512, PS_FULL, nullptr, nullptr);
    float* lnout = (l == 3) ? (float*)d_out : xf;
    ln_sum<4><<<ROWS, 256, 0, stream>>>(xf, pblk, PS_FULL, ln3g, ln3b, (size_t)l * 512, flags, lnout);
  }
}

// Round 5
// 2601.746 us; speedup vs baseline: 1.2114x; 1.0673x over previous
//
#include <hip/hip_runtime.h>
#include <math.h>

typedef __bf16 bf16;
typedef unsigned short u16;
typedef __bf16 bf16x8 __attribute__((ext_vector_type(8)));
typedef float f32x4 __attribute__((ext_vector_type(4)));

#define T_SEQ 2048
#define NB    2
#define CE    512
#define NH    8
#define HD    64
#define ROWS  4096
#define NBH   16
#define LDT   40   // GEMM LDS stride (32+8)
#define LDA   72   // attn LDS stride (64+8)

#define MFMA16(a,b,c) __builtin_amdgcn_mfma_f32_16x16x32_bf16((a),(b),(c),0,0,0)

// bijective XCD-chunked swizzle (m204): round-robin pos -> contiguous chunk
static __device__ __forceinline__ int xcd_swz(int id, int n) {
  int q = n >> 3, r = n & 7;
  int x = id & 7, o = id >> 3;
  return (x < r) ? (x * (q + 1) + o) : (r * (q + 1) + (x - r) * q + o);
}

// =====================================================================
// Sniffer: flags[0]=1 if float inputs are fp32 storage; flags[1]=1 if tokens int64
// =====================================================================
__global__ __launch_bounds__(256) void sniff(const u16* __restrict__ xs,
                                             const int* __restrict__ toks,
                                             int* __restrict__ flags)
{
  const int tid = threadIdx.x;
  int crazy = 0, ze = 0;
  for (int i = tid; i < 4096; i += 256) {
    int e = (xs[i] >> 7) & 0xFF;
    if (e >= 141) crazy++;
    if (((i & 1) == 0) && (xs[i] == 0)) ze++;
  }
  int zc = 0;
  for (int i = tid; i < 1024; i += 256)
    if (toks[2 * i + 1] == 0) zc++;
  __shared__ int r1[4], r2[4], r3[4];
#pragma unroll
  for (int o = 32; o; o >>= 1) {
    crazy += __shfl_down(crazy, o); ze += __shfl_down(ze, o); zc += __shfl_down(zc, o);
  }
  if ((tid & 63) == 0) { r1[tid >> 6] = crazy; r2[tid >> 6] = ze; r3[tid >> 6] = zc; }
  __syncthreads();
  if (tid == 0) {
    int c = r1[0] + r1[1] + r1[2] + r1[3];
    int z = r2[0] + r2[1] + r2[2] + r2[3];
    int t = r3[0] + r3[1] + r3[2] + r3[3];
    flags[0] = (z > 1500 || c > 64) ? 1 : 0;
    flags[1] = (t > 900) ? 1 : 0;
  }
}

static __device__ __forceinline__ float ldf(const void* src, size_t eoff, bool f32) {
  return f32 ? ((const float*)src)[eoff] : (float)((const bf16*)src)[eoff];
}

// =====================================================================
// Positional embedding
// =====================================================================
__global__ __launch_bounds__(256) void posembed(const void* __restrict__ xsrc,
                                                const int* __restrict__ toks,
                                                const int* __restrict__ flags,
                                                float* __restrict__ xf)
{
  const bool f32 = flags[0] != 0;
  const bool tok64 = flags[1] != 0;
  const int row = blockIdx.x;
  const int t = row >> 1, b = row & 1;
  const int tix = b * T_SEQ + t;
  const int tok = tok64 ? toks[2 * tix] : toks[tix];
  const int p = (tok != 0) ? (t + 1) : 0;
  const float kf = -0.0361193740f;
  for (int c = threadIdx.x; c < CE; c += 256) {
    float pe = 0.0f;
    if (p != 0) {
      int i = (c < 256) ? c : (c - 256);
      float freq = expf((float)i * kf);
      float ang = (float)p * freq;
      pe = (c < 256) ? sinf(ang) : cosf(ang);
    }
    xf[(size_t)row * CE + c] = ldf(xsrc, (size_t)row * CE + c, f32) + pe;
  }
}

// =====================================================================
// MFMA GEMM: 1D grid + XCD swizzle, double-buffered LDS (1 barrier/K-step),
// split-K (z), global->reg prefetch. Split-bf16 3-term numerics.
// A source: fp32 ws buffer for bx<nbxA, raw input A2 (dtype by flag) else
// (lets cross-attn q[xf] and k/v[enc] share one N=1536 dispatch).
// AFFINE: a' = inv*a - (mn*inv)*vsum  (attention norm folded into Wo).
// =====================================================================
template<bool RELUF, bool AFFINE>
__global__ __launch_bounds__(256) void gemm_mfma(const float* __restrict__ A,
                                                 const void* __restrict__ A2,
                                                 const void* __restrict__ Bw, size_t bwOff,
                                                 const void* __restrict__ bias, size_t biasOff,
                                                 const int* __restrict__ flags,
                                                 float* __restrict__ Cf,
                                                 int N, int K, int kspan,
                                                 int nbx, int nbxA,
                                                 long long partStride,
                                                 const float* __restrict__ mmf,
                                                 const float* __restrict__ vsum)
{
  __shared__ __align__(16) bf16 AhS[2][128 * LDT];
  __shared__ __align__(16) bf16 AlS[2][128 * LDT];
  __shared__ __align__(16) bf16 BhS[2][128 * LDT];
  __shared__ __align__(16) bf16 BlS[2][128 * LDT];
  const int fl = flags[0];
  const int nblk = nbx * (int)1;  // placeholder (nby folded below)
  (void)nblk;
  const int id = xcd_swz((int)blockIdx.x, (int)gridDim.x);
  // decode: bx fastest, then by, then z. nby inferred from grid and kspan count.
  // grid = nbx * nby * nz ; we pass nbx and compute per-axis from totals.
  // caller guarantees: nby = 32 for all launches (M = 4096 rows).
  const int per_z = nbx * 32;
  const int zz = id / per_z;
  const int rem = id - zz * per_z;
  const int by = rem / nbx, bx = rem - by * nbx;
  const bool a_f32 = (bx < nbxA) ? true : (fl != 0);
  const void* Abase = (bx < nbxA) ? (const void*)A : A2;
  const bool b_f32 = (fl != 0);
  const int tid = threadIdx.x;
  const int m0 = by * 128, n0 = bx * 128;
  const int srow = tid >> 1;
  const int skc  = (tid & 1) * 16;
  const int wid = tid >> 6, lane = tid & 63;
  const int wm = (wid >> 1) * 64, wn = (wid & 1) * 64;
  const int fr = lane & 15;
  const int fk = (lane >> 4) * 8;
  const int kb = zz * kspan;
  const int ke = (kb + kspan < K) ? (kb + kspan) : K;
  float* Cp = Cf + (long long)zz * partStride;
  const int arow1 = (m0 + srow) & 1;
  float inv_ = 0.0f, cmn_ = 0.0f;
  if (AFFINE) { inv_ = 1.0f / (mmf[1] - mmf[0]); cmn_ = mmf[0] * inv_; }
  f32x4 acc[4][4] = {};

  uint4 ra[4], rb[4];
  auto loadA = [&](int k0) {
    size_t g = (size_t)(m0 + srow) * K + k0 + skc;
    if (a_f32) {
      const uint4* p = (const uint4*)((const float*)Abase + g);
      ra[0] = p[0]; ra[1] = p[1]; ra[2] = p[2]; ra[3] = p[3];
    } else {
      const uint4* p = (const uint4*)((const bf16*)Abase + g);
      ra[0] = p[0]; ra[1] = p[1];
    }
  };
  auto loadB = [&](int k0) {
    size_t g = bwOff + (size_t)(n0 + srow) * K + k0 + skc;
    if (b_f32) {
      const uint4* p = (const uint4*)((const float*)Bw + g);
      rb[0] = p[0]; rb[1] = p[1]; rb[2] = p[2]; rb[3] = p[3];
    } else {
      const uint4* p = (const uint4*)((const bf16*)Bw + g);
      rb[0] = p[0]; rb[1] = p[1];
    }
  };
  auto fixA = [&](int k0) {
    if (AFFINE) {
      float* f = (float*)ra;
      const float* vs = vsum + arow1 * 512 + k0 + skc;
#pragma unroll
      for (int q = 0; q < 16; q++) f[q] = inv_ * f[q] - cmn_ * vs[q];
    }
  };
  auto cvtStore = [&](const uint4* r, bool f32src, bool wantLo, bf16* Hs, bf16* Ls) {
    float v[16];
    if (f32src) {
      const float* f = (const float*)r;
#pragma unroll
      for (int q = 0; q < 16; q++) v[q] = f[q];
    } else {
      const bf16* c = (const bf16*)r;
#pragma unroll
      for (int q = 0; q < 16; q++) v[q] = (float)c[q];
    }
    bf16x8 h0, h1, l0, l1;
#pragma unroll
    for (int q = 0; q < 8; q++) {
      bf16 ha = (bf16)v[q], hb = (bf16)v[8 + q];
      h0[q] = ha; h1[q] = hb;
      l0[q] = (bf16)(v[q]     - (float)ha);
      l1[q] = (bf16)(v[8 + q] - (float)hb);
    }
    *(bf16x8*)&Hs[srow * LDT + skc]     = h0;
    *(bf16x8*)&Hs[srow * LDT + skc + 8] = h1;
    if (wantLo) {
      *(bf16x8*)&Ls[srow * LDT + skc]     = l0;
      *(bf16x8*)&Ls[srow * LDT + skc + 8] = l1;
    }
  };

  // prologue: stage k=kb into buf0, prefetch k=kb+32
  loadA(kb); loadB(kb);
  fixA(kb);
  cvtStore(ra, a_f32, a_f32, AhS[0], AlS[0]);
  cvtStore(rb, b_f32, b_f32, BhS[0], BlS[0]);
  if (kb + 32 < ke) { loadA(kb + 32); loadB(kb + 32); }

  int cur = 0;
  for (int k0 = kb; k0 < ke; k0 += 32) {
    __syncthreads();   // buf[cur] staged & prior reads of buf[cur^1] done
    if (k0 + 32 < ke) {
      fixA(k0 + 32);
      cvtStore(ra, a_f32, a_f32, AhS[cur ^ 1], AlS[cur ^ 1]);
      cvtStore(rb, b_f32, b_f32, BhS[cur ^ 1], BlS[cur ^ 1]);
      if (k0 + 64 < ke) { loadA(k0 + 64); loadB(k0 + 64); }
    }
    const bf16* Ahc = AhS[cur]; const bf16* Alc = AlS[cur];
    const bf16* Bhc = BhS[cur]; const bf16* Blc = BlS[cur];
    bf16x8 ah[4], bh[4];
#pragma unroll
    for (int i = 0; i < 4; i++) ah[i] = *(const bf16x8*)&Ahc[(wm + i*16 + fr) * LDT + fk];
#pragma unroll
    for (int j = 0; j < 4; j++) bh[j] = *(const bf16x8*)&Bhc[(wn + j*16 + fr) * LDT + fk];
#pragma unroll
    for (int i = 0; i < 4; i++)
#pragma unroll
      for (int j = 0; j < 4; j++)
        acc[i][j] = MFMA16(ah[i], bh[j], acc[i][j]);
    if (a_f32) {
      bf16x8 al[4];
#pragma unroll
      for (int i = 0; i < 4; i++) al[i] = *(const bf16x8*)&Alc[(wm + i*16 + fr) * LDT + fk];
#pragma unroll
      for (int i = 0; i < 4; i++)
#pragma unroll
        for (int j = 0; j < 4; j++)
          acc[i][j] = MFMA16(al[i], bh[j], acc[i][j]);
    }
    if (b_f32) {
      bf16x8 bl[4];
#pragma unroll
      for (int j = 0; j < 4; j++) bl[j] = *(const bf16x8*)&Blc[(wn + j*16 + fr) * LDT + fk];
#pragma unroll
      for (int i = 0; i < 4; i++)
#pragma unroll
        for (int j = 0; j < 4; j++)
          acc[i][j] = MFMA16(ah[i], bl[j], acc[i][j]);
    }
    cur ^= 1;
  }
  const int orow0 = m0 + wm + (lane >> 4) * 4;
  const int ocol0 = n0 + wn + (lane & 15);
  const bool addb = (zz == 0);
#pragma unroll
  for (int j = 0; j < 4; j++) {
    int col = ocol0 + j * 16;
    float bv = addb ? ldf(bias, biasOff + col, b_f32) : 0.0f;
#pragma unroll
    for (int i = 0; i < 4; i++) {
#pragma unroll
      for (int r = 0; r < 4; r++) {
        float vv = acc[i][j][r] + bv;
        if (RELUF) vv = fmaxf(vv, 0.0f);
        Cp[(size_t)(orow0 + i * 16 + r) * N + col] = vv;
      }
    }
  }
}

// =====================================================================
// Fused K/V prepass: K split -> kh/kl [bh][s][64]; V transpose+split ->
// vth/vtl [bh][d][s]; per-64-chunk V col sums -> vcs[bh][32][64].
// grid (16 bh, 32 s-blocks of 64)
// =====================================================================
__global__ __launch_bounds__(256) void prep_kv(const float* __restrict__ base, int ld,
                                               int kofs0, int vofs0,
                                               bf16* __restrict__ kh, bf16* __restrict__ kl,
                                               bf16* __restrict__ vth, bf16* __restrict__ vtl,
                                               float* __restrict__ vcs)
{
  __shared__ float ts[64 * 65];
  const int bh = blockIdx.x, s0 = blockIdx.y * 64;
  const int b = bh >> 3, h = bh & 7;
  const int kofs = kofs0 + h * HD, vofs = vofs0 + h * HD;
  const int tid = threadIdx.x;
#pragma unroll
  for (int it = 0; it < 16; ++it) {
    int idx = it * 256 + tid, r = idx >> 6, d = idx & 63;
    size_t rowb = (size_t)((s0 + r) * NB + b) * ld;
    float v = base[rowb + kofs + d];
    bf16 hi = (bf16)v;
    size_t o = ((size_t)bh * T_SEQ + s0 + r) * 64 + d;
    kh[o] = hi; kl[o] = (bf16)(v - (float)hi);
    ts[r * 65 + d] = base[rowb + vofs + d];
  }
  __syncthreads();
  const int d = tid >> 2, sseg = (tid & 3) * 16;
  bf16x8 hv0, lv0, hv1, lv1;
#pragma unroll
  for (int q = 0; q < 8; ++q) {
    float v0 = ts[(sseg + q) * 65 + d];
    float v1 = ts[(sseg + 8 + q) * 65 + d];
    bf16 h0 = (bf16)v0, h1 = (bf16)v1;
    hv0[q] = h0; lv0[q] = (bf16)(v0 - (float)h0);
    hv1[q] = h1; lv1[q] = (bf16)(v1 - (float)h1);
  }
  size_t o = ((size_t)bh * 64 + d) * T_SEQ + s0 + sseg;
  *(bf16x8*)&vth[o]     = hv0;
  *(bf16x8*)&vth[o + 8] = hv1;
  *(bf16x8*)&vtl[o]     = lv0;
  *(bf16x8*)&vtl[o + 8] = lv1;
  if (tid < 64) {
    float s = 0.0f;
    for (int j = 0; j < 64; ++j) s += ts[j * 65 + tid];
    vcs[((size_t)bh * 32 + blockIdx.y) * 64 + tid] = s;
  }
}

// pair heavy/light causal blocks
__device__ __forceinline__ int remap_ty(int ty) { return (ty < 16) ? ty : 47 - ty; }

// =====================================================================
// Fused attention pass (affine trick): raw masked scores w (masked->0),
// global min/max partials, raw PV = sum_s w*v (independent of mn/mx).
// Normalization deferred to the Wo GEMM (AFFINE). 1D grid 512 + XCD swz
// (same-bh t-blocks contiguous -> K/V panels L2-resident per XCD).
// =====================================================================
template<bool MASK>
__global__ __launch_bounds__(256) void fattn(const float* __restrict__ qbase, int qld, int qofs0,
                                             const bf16* __restrict__ kh, const bf16* __restrict__ kl,
                                             const bf16* __restrict__ vth, const bf16* __restrict__ vtl,
                                             float* __restrict__ partial,
                                             float* __restrict__ pvout)
{
  __shared__ __align__(16) bf16 Qh[64 * LDA], Ql[64 * LDA];
  __shared__ __align__(16) bf16 Kh[64 * LDA], Kl[64 * LDA];
  __shared__ __align__(16) bf16 Vh[64 * LDA], Vl[64 * LDA];
  __shared__ __align__(16) bf16 Ph[64 * LDA], Pl[64 * LDA];
  __shared__ float rn[4], rx[4];
  const int id = xcd_swz((int)blockIdx.x, 512);
  const int bh = id >> 5;
  const int tyr = remap_ty(id & 31);
  const int t0 = tyr * 64;
  const int b = bh >> 3, h = bh & 7;
  const int qofs = qofs0 + h * HD;
  const int tid = threadIdx.x;
#pragma unroll
  for (int it = 0; it < 16; ++it) {
    int idx = it * 256 + tid, r = idx >> 6, d = idx & 63;
    float v = qbase[(size_t)((t0 + r) * NB + b) * qld + qofs + d] * 0.125f;
    bf16 hi = (bf16)v;
    Qh[r * LDA + d] = hi; Ql[r * LDA + d] = (bf16)(v - (float)hi);
  }
  const int wid = tid >> 6, lane = tid & 63;
  const int wm_ = (wid >> 1) * 32, wn_ = (wid & 1) * 32;
  const int fr = lane & 15, fko = (lane >> 4) * 8;
  const int crr = (lane >> 4) * 4, crc = lane & 15;
  const int cr = tid >> 2, cseg = (tid & 3) * 16;
  float mn = 1e30f, mx = -1e30f;
  f32x4 o4[2][2] = {};
  const int nch = MASK ? (tyr + 1) : 32;
  for (int sc = 0; sc < nch; ++sc) {
    const int s0 = sc * 64;
    __syncthreads();
    {
      size_t go = ((size_t)bh * T_SEQ + s0 + cr) * 64 + cseg;
      *(bf16x8*)&Kh[cr * LDA + cseg]     = *(const bf16x8*)&kh[go];
      *(bf16x8*)&Kh[cr * LDA + cseg + 8] = *(const bf16x8*)&kh[go + 8];
      *(bf16x8*)&Kl[cr * LDA + cseg]     = *(const bf16x8*)&kl[go];
      *(bf16x8*)&Kl[cr * LDA + cseg + 8] = *(const bf16x8*)&kl[go + 8];
      size_t gv = ((size_t)bh * 64 + cr) * T_SEQ + s0 + cseg;
      *(bf16x8*)&Vh[cr * LDA + cseg]     = *(const bf16x8*)&vth[gv];
      *(bf16x8*)&Vh[cr * LDA + cseg + 8] = *(const bf16x8*)&vth[gv + 8];
      *(bf16x8*)&Vl[cr * LDA + cseg]     = *(const bf16x8*)&vtl[gv];
      *(bf16x8*)&Vl[cr * LDA + cseg + 8] = *(const bf16x8*)&vtl[gv + 8];
    }
    __syncthreads();
    // ---- QK^T (3-term) ----
    f32x4 a4[2][2] = {};
#pragma unroll
    for (int ks = 0; ks < 2; ++ks) {
      bf16x8 aH[2], aL[2], bH[2], bL[2];
#pragma unroll
      for (int i = 0; i < 2; ++i) {
        aH[i] = *(const bf16x8*)&Qh[(wm_ + i*16 + fr) * LDA + ks*32 + fko];
        aL[i] = *(const bf16x8*)&Ql[(wm_ + i*16 + fr) * LDA + ks*32 + fko];
        bH[i] = *(const bf16x8*)&Kh[(wn_ + i*16 + fr) * LDA + ks*32 + fko];
        bL[i] = *(const bf16x8*)&Kl[(wn_ + i*16 + fr) * LDA + ks*32 + fko];
      }
#pragma unroll
      for (int i = 0; i < 2; ++i)
#pragma unroll
        for (int j = 0; j < 2; ++j) {
          a4[i][j] = MFMA16(aH[i], bH[j], a4[i][j]);
          a4[i][j] = MFMA16(aL[i], bH[j], a4[i][j]);
          a4[i][j] = MFMA16(aH[i], bL[j], a4[i][j]);
        }
    }
    // ---- mask, min/max, store raw w hi/lo ----
#pragma unroll
    for (int i = 0; i < 2; ++i)
#pragma unroll
      for (int j = 0; j < 2; ++j)
#pragma unroll
        for (int r = 0; r < 4; ++r) {
          int tl = wm_ + i*16 + crr + r;
          int sl = wn_ + j*16 + crc;
          float w = a4[i][j][r];
          if (MASK && (s0 + sl) > (t0 + tl)) w = 0.0f;
          mn = fminf(mn, w); mx = fmaxf(mx, w);
          bf16 wh = (bf16)w;
          Ph[tl * LDA + sl] = wh;
          Pl[tl * LDA + sl] = (bf16)(w - (float)wh);
        }
    __syncthreads();
    // ---- raw PV (3-term) ----
#pragma unroll
    for (int ks = 0; ks < 2; ++ks) {
      bf16x8 pH[2], pL[2], vH[2], vL[2];
#pragma unroll
      for (int i = 0; i < 2; ++i) {
        pH[i] = *(const bf16x8*)&Ph[(wm_ + i*16 + fr) * LDA + ks*32 + fko];
        pL[i] = *(const bf16x8*)&Pl[(wm_ + i*16 + fr) * LDA + ks*32 + fko];
        vH[i] = *(const bf16x8*)&Vh[(wn_ + i*16 + fr) * LDA + ks*32 + fko];
        vL[i] = *(const bf16x8*)&Vl[(wn_ + i*16 + fr) * LDA + ks*32 + fko];
      }
#pragma unroll
      for (int i = 0; i < 2; ++i)
#pragma unroll
        for (int j = 0; j < 2; ++j) {
          o4[i][j] = MFMA16(pH[i], vH[j], o4[i][j]);
          o4[i][j] = MFMA16(pL[i], vH[j], o4[i][j]);
          o4[i][j] = MFMA16(pH[i], vL[j], o4[i][j]);
        }
    }
  }
#pragma unroll
  for (int i = 0; i < 2; ++i)
#pragma unroll
    for (int j = 0; j < 2; ++j)
#pragma unroll
      for (int r = 0; r < 4; ++r) {
        int tl = wm_ + i*16 + crr + r;
        int dl = wn_ + j*16 + crc;
        pvout[(size_t)((t0 + tl) * NB + b) * CE + h * HD + dl] = o4[i][j][r];
      }
#pragma unroll
  for (int o = 32; o; o >>= 1) { mn = fminf(mn, __shfl_down(mn, o)); mx = fmaxf(mx, __shfl_down(mx, o)); }
  if (lane == 0) { rn[wid] = mn; rx[wid] = mx; }
  __syncthreads();
  if (tid == 0) {
    partial[2 * id]     = fminf(fminf(rn[0], rn[1]), fminf(rn[2], rn[3]));
    partial[2 * id + 1] = fmaxf(fmaxf(rx[0], rx[1]), fmaxf(rx[2], rx[3]));
  }
}

// =====================================================================
// reduce 512 partial pairs -> mmf; total V colsum vsum[2*512]
// =====================================================================
__global__ __launch_bounds__(512) void reduce_mm(const float* __restrict__ partial,
                                                 const float* __restrict__ vcs,
                                                 float* __restrict__ mmf,
                                                 float* __restrict__ vsum)
{
  const int tid = threadIdx.x, w = tid >> 6, l = tid & 63;
  __shared__ float rn[8], rx[8];
  float mn = partial[2 * tid], mx = partial[2 * tid + 1];
#pragma unroll
  for (int o = 32; o; o >>= 1) { mn = fminf(mn, __shfl_down(mn, o)); mx = fmaxf(mx, __shfl_down(mx, o)); }
  if (l == 0) { rn[w] = mn; rx[w] = mx; }
  __syncthreads();
  if (tid == 0) {
    float a = 1e30f, c = -1e30f;
#pragma unroll
    for (int i = 0; i < 8; i++) { a = fminf(a, rn[i]); c = fmaxf(c, rx[i]); }
    mmf[0] = a; mmf[1] = c;
  }
  for (int e = tid; e < 1024; e += 512) {
    int bh = e >> 6, d = e & 63;
    float s = 0.0f;
#pragma unroll
    for (int ch = 0; ch < 32; ++ch) s += vcs[(size_t)bh * 2048 + ch * 64 + d];
    vsum[e] = s;
  }
}

// =====================================================================
// LayerNorm(res + sum of NP partial buffers)
// =====================================================================
template<int NP>
__global__ __launch_bounds__(256) void ln_sum(const float* __restrict__ res,
                                              const float* __restrict__ p, long long pstride,
                                              const void* __restrict__ g, const void* __restrict__ be,
                                              size_t goff, const int* __restrict__ flags,
                                              float* __restrict__ xfo)
{
  __shared__ float red[4];
  const bool fl = flags[0] != 0;
  const int tid = threadIdx.x;
  const size_t base = (size_t)blockIdx.x * CE;
  float a  = res[base + tid];
  float b2 = res[base + tid + 256];
#pragma unroll
  for (int k = 0; k < NP; k++) {
    a  += p[(long long)k * pstride + base + tid];
    b2 += p[(long long)k * pstride + base + tid + 256];
  }
  float s = a + b2;
#pragma unroll
  for (int o = 32; o; o >>= 1) s += __shfl_down(s, o);
  if ((tid & 63) == 0) red[tid >> 6] = s;
  __syncthreads();
  float mu = (red[0] + red[1] + red[2] + red[3]) * (1.0f / 512.0f);
  __syncthreads();
  float da = a - mu, db = b2 - mu;
  float q = da * da + db * db;
#pragma unroll
  for (int o = 32; o; o >>= 1) q += __shfl_down(q, o);
  if ((tid & 63) == 0) red[tid >> 6] = q;
  __syncthreads();
  float var = (red[0] + red[1] + red[2] + red[3]) * (1.0f / 512.0f);
  float rs = rsqrtf(var + 1e-20f);
  xfo[base + tid]       = da * rs * ldf(g, goff + tid, fl)       + ldf(be, goff + tid, fl);
  xfo[base + tid + 256] = db * rs * ldf(g, goff + tid + 256, fl) + ldf(be, goff + tid + 256, fl);
}

// =====================================================================
extern "C" void kernel_launch(void* const* d_in, const int* in_sizes, int n_in,
                              void* d_out, int out_size, void* d_ws, size_t ws_size,
                              hipStream_t stream)
{
  (void)in_sizes; (void)n_in; (void)out_size; (void)ws_size;
  const void* x_in   = d_in[0];
  const void* enc_in = d_in[1];
  const int*  tokens = (const int*)d_in[2];
  const void* sWqkv = d_in[3];
  const void* sbqkv = d_in[4];
  const void* sWo   = d_in[5];
  const void* sbo   = d_in[6];
  const void* cWqkv = d_in[7];
  const void* cbqkv = d_in[8];
  const void* cWo   = d_in[9];
  const void* cbo   = d_in[10];
  const void* fc1w  = d_in[11];
  const void* fc1b  = d_in[12];
  const void* fc2w  = d_in[13];
  const void* fc2b  = d_in[14];
  const void* ln1g  = d_in[15];
  const void* ln1b  = d_in[16];
  const void* ln2g  = d_in[17];
  const void* ln2b  = d_in[18];
  const void* ln3g  = d_in[19];
  const void* ln3b  = d_in[20];

  char* ws = (char*)d_ws;
  size_t off = 0;
  auto alloc = [&](size_t bytes) -> char* {
    char* p = ws + off;
    off += (bytes + 255) & ~(size_t)255;
    return p;
  };
  int*   flags   = (int*)  alloc(256);
  float* mmf     = (float*)alloc(256);
  float* vsum    = (float*)alloc(1024 * 4);
  float* partial = (float*)alloc(4096);
  float* xf      = (float*)alloc((size_t)ROWS * CE * 4);        //  8 MiB residual
  float* y       = (float*)alloc((size_t)ROWS * CE * 4);        //  8 MiB attn raw-PV
  float* qkv     = (float*)alloc((size_t)ROWS * 2048 * 4);      // 32 MiB proj / FFN h
  float* pblk    = (float*)alloc((size_t)ROWS * CE * 4 * 4);    // 32 MiB split-K partials
  bf16*  khb     = (bf16*) alloc((size_t)16 * T_SEQ * 64 * 2);  // 4 MiB
  bf16*  klb     = (bf16*) alloc((size_t)16 * T_SEQ * 64 * 2);  // 4 MiB
  bf16*  vth     = (bf16*) alloc((size_t)16 * 64 * T_SEQ * 2);  // 4 MiB
  bf16*  vtl     = (bf16*) alloc((size_t)16 * 64 * T_SEQ * 2);  // 4 MiB
  float* vcs     = (float*)alloc((size_t)16 * 32 * 64 * 4);     // 128 KiB
  const long long PS_FULL = (long long)ROWS * CE;

  sniff<<<1, 256, 0, stream>>>((const u16*)x_in, tokens, flags);
  posembed<<<ROWS, 256, 0, stream>>>(x_in, tokens, flags, xf);

  for (int l = 0; l < 4; l++) {
    // ---------------- self-attention ----------------
    gemm_mfma<false, false><<<384, 256, 0, stream>>>(
        xf, xf, sWqkv, (size_t)l * 1536 * 512, sbqkv, (size_t)l * 1536, flags, qkv,
        1536, 512, 512, 12, 12, 0, nullptr, nullptr);
    prep_kv<<<dim3(16, 32), 256, 0, stream>>>(qkv, 1536, 512, 1024, khb, klb, vth, vtl, vcs);
    fattn<true><<<512, 256, 0, stream>>>(qkv, 1536, 0, khb, klb, vth, vtl, partial, y);
    reduce_mm<<<1, 512, 0, stream>>>(partial, vcs, mmf, vsum);
    gemm_mfma<false, true><<<512, 256, 0, stream>>>(   // AFFINE Wo, split-K4
        y, y, sWo, (size_t)l * 512 * 512, sbo, (size_t)l * 512, flags, pblk,
        512, 512, 128, 4, 4, PS_FULL, mmf, vsum);
    ln_sum<4><<<ROWS, 256, 0, stream>>>(xf, pblk, PS_FULL, ln1g, ln1b, (size_t)l * 512, flags, xf);

    // ---------------- cross-attention (merged q|kv projection, N=1536) ----------------
    gemm_mfma<false, false><<<384, 256, 0, stream>>>(
        xf, enc_in, cWqkv, (size_t)l * 1536 * 512, cbqkv, (size_t)l * 1536, flags, qkv,
        1536, 512, 512, 12, 4 /* bx<4 -> A=xf (q); bx>=4 -> A=enc (k,v) */, 0, nullptr, nullptr);
    prep_kv<<<dim3(16, 32), 256, 0, stream>>>(qkv, 1536, 512, 1024, khb, klb, vth, vtl, vcs);
    fattn<false><<<512, 256, 0, stream>>>(qkv, 1536, 0, khb, klb, vth, vtl, partial, y);
    reduce_mm<<<1, 512, 0, stream>>>(partial, vcs, mmf, vsum);
    gemm_mfma<false, true><<<512, 256, 0, stream>>>(   // AFFINE cWo, split-K4
        y, y, cWo, (size_t)l * 512 * 512, cbo, (size_t)l * 512, flags, pblk,
        512, 512, 128, 4, 4, PS_FULL, mmf, vsum);
    ln_sum<4><<<ROWS, 256, 0, stream>>>(xf, pblk, PS_FULL, ln2g, ln2b, (size_t)l * 512, flags, xf);

    // ---------------- FFN (batched M=4096) ----------------
    gemm_mfma<true, false><<<512, 256, 0, stream>>>(
        xf, xf, fc1w, (size_t)l * 2048 * 512, fc1b, (size_t)l * 2048, flags, qkv,
        2048, 512, 512, 16, 16, 0, nullptr, nullptr);
    gemm_mfma<false, false><<<512, 256, 0, stream>>>(  // split-K4
        qkv, qkv, fc2w, (size_t)l * 512 * 2048, fc2b, (size_t)l * 512, flags, pblk,
        512, 2048, 512, 4, 4, PS_FULL, nullptr, nullptr);
    float* lnout = (l == 3) ? (float*)d_out : xf;
    ln_sum<4><<<ROWS, 256, 0, stream>>>(xf, pblk, PS_FULL, ln3g, ln3b, (size_t)l * 512, flags, lnout);
  }
}